// Round 1
// baseline (540.670 us; speedup 1.0000x reference)
//
#include <hip/hip_runtime.h>
#include <hip/hip_bf16.h>
#include <stdint.h>

#define DIM   768
#define NOUT  2304        // 3*DIM
#define MTOK  32768       // 8*64*64
#define KD    768
#define RANK  16

typedef float          f32x4 __attribute__((ext_vector_type(4)));
typedef short          s16x8 __attribute__((ext_vector_type(8)));
typedef unsigned short u16;
typedef u16            u16x8 __attribute__((ext_vector_type(8)));

static constexpr size_t WB_ELEMS = (size_t)NOUT * KD;   // 1,769,472
static constexpr size_t XB_ELEMS = (size_t)MTOK * KD;   // 25,165,824

// f32 -> bf16 round-to-nearest-even (inputs are finite, no NaN handling needed)
__device__ __forceinline__ u16 f2bf(float f) {
  union { float f; uint32_t u; } v; v.f = f;
  uint32_t u = v.u;
  return (u16)((u + 0x7FFFu + ((u >> 16) & 1u)) >> 16);
}

__device__ __forceinline__ void gload_lds16(const void* g, void* l) {
  __builtin_amdgcn_global_load_lds(
      (const __attribute__((address_space(1))) unsigned int*)g,
      (__attribute__((address_space(3))) unsigned int*)l, 16, 0, 0);
}

// ---------------------------------------------------------------------------
// prep: W_eff[n][k] = Wqkv[n][k] + sum_r B_s[n%768][r] * A_s[r][k]  -> bf16
// one thread per element; 768 % 256 == 0 so s is block-uniform (no divergence)
// ---------------------------------------------------------------------------
__global__ __launch_bounds__(256) void prep_w(
    const float* __restrict__ Wqkv,
    const float* __restrict__ Aq, const float* __restrict__ Bq,
    const float* __restrict__ Ak, const float* __restrict__ Bk,
    const float* __restrict__ Av, const float* __restrict__ Bv,
    u16* __restrict__ Wb)
{
  int flat = blockIdx.x * 256 + threadIdx.x;       // < NOUT*KD
  int n = flat / KD;
  int k = flat - n * KD;
  int s = n / DIM;
  int d = n - s * DIM;
  const float* A = (s == 0) ? Aq : ((s == 1) ? Ak : Av);
  const float* B = (s == 0) ? Bq : ((s == 1) ? Bk : Bv);
  float acc = Wqkv[(size_t)n * KD + k];
#pragma unroll
  for (int r = 0; r < RANK; ++r)
    acc += B[d * RANK + r] * A[r * KD + k];
  Wb[(size_t)n * KD + k] = f2bf(acc);
}

// ---------------------------------------------------------------------------
// x f32 -> bf16 (8 elems/thread, 32B load / 16B store)
// ---------------------------------------------------------------------------
__global__ __launch_bounds__(256) void conv_x(
    const float* __restrict__ x, u16* __restrict__ xb)
{
  size_t base = ((size_t)blockIdx.x * 256 + threadIdx.x) * 8;
  const float4* p = (const float4*)(x + base);
  float4 f0 = p[0];
  float4 f1 = p[1];
  u16x8 o;
  o[0] = f2bf(f0.x); o[1] = f2bf(f0.y); o[2] = f2bf(f0.z); o[3] = f2bf(f0.w);
  o[4] = f2bf(f1.x); o[5] = f2bf(f1.y); o[6] = f2bf(f1.z); o[7] = f2bf(f1.w);
  *(u16x8*)(xb + base) = o;
}

// ---------------------------------------------------------------------------
// GEMM: out[m][n] = sum_k xb[m][k] * Wb[n][k] + bias[n]   (both K-major)
// 128x128 tile, BK=32, 4 waves (2x2), each wave 64x64 = 4x4 frags of 16x16.
// mfma_f32_16x16x32_bf16; verified fragment mapping: lane reads 8 contiguous
// k at (lane%16 -> row/col, lane/16 -> k-group); C/D: col=lane&15,
// row=(lane>>4)*4+reg.
// ---------------------------------------------------------------------------
template <bool XPRE>
__global__ __launch_bounds__(256) void gemm_kern(
    const float* __restrict__ x,    // used when !XPRE
    const u16*   __restrict__ xb,   // used when XPRE
    const u16*   __restrict__ Wb,
    const float* __restrict__ bias,
    float* __restrict__ out)
{
  __shared__ __attribute__((aligned(16))) u16 As[128 * 32];
  __shared__ __attribute__((aligned(16))) u16 Bs[128 * 32];

  const int tid  = threadIdx.x;
  const int wave = tid >> 6;
  const int lane = tid & 63;

  // XCD-chunked bijective swizzle: nwg=4608, 4608/8=576
  int bid = blockIdx.x;
  int swz = (bid & 7) * 576 + (bid >> 3);
  int tm  = swz / 18;
  int tn  = swz - tm * 18;
  const int m0 = tm * 128;
  const int n0 = tn * 128;

  const int wr = (wave >> 1) * 64;   // wave row offset in tile
  const int wc = (wave & 1) * 64;    // wave col offset in tile

  const int fr = lane & 15;          // fragment row/col index
  const int fq = lane >> 4;          // k-group / row-quad

  f32x4 acc[4][4];
#pragma unroll
  for (int i = 0; i < 4; ++i)
#pragma unroll
    for (int j = 0; j < 4; ++j) acc[i][j] = (f32x4)0.0f;

  for (int kk = 0; kk < KD / 32; ++kk) {
    const int k0 = kk * 32;
    __syncthreads();   // previous tile's compute done before overwrite

    // ---- stage W tile (always global_load_lds, 16B/lane) ----
#pragma unroll
    for (int s2 = 0; s2 < 2; ++s2) {
      int seg = wave * 2 + s2;                       // 8 segs of 16 rows
      int row = seg * 16 + (lane >> 2);
      const u16* g = Wb + (size_t)(n0 + row) * KD + k0 + (lane & 3) * 8;
      gload_lds16(g, &Bs[seg * 16 * 32]);            // wave-uniform LDS base
    }

    // ---- stage x tile ----
    if constexpr (XPRE) {
#pragma unroll
      for (int s2 = 0; s2 < 2; ++s2) {
        int seg = wave * 2 + s2;
        int row = seg * 16 + (lane >> 2);
        const u16* g = xb + (size_t)(m0 + row) * KD + k0 + (lane & 3) * 8;
        gload_lds16(g, &As[seg * 16 * 32]);
      }
    } else {
#pragma unroll
      for (int i = 0; i < 2; ++i) {
        int r = (tid >> 2) + i * 64;
        int c = (tid & 3) * 8;
        const float* g = x + (size_t)(m0 + r) * KD + k0 + c;
        float4 f0 = *(const float4*)g;
        float4 f1 = *(const float4*)(g + 4);
        u16x8 o;
        o[0] = f2bf(f0.x); o[1] = f2bf(f0.y); o[2] = f2bf(f0.z); o[3] = f2bf(f0.w);
        o[4] = f2bf(f1.x); o[5] = f2bf(f1.y); o[6] = f2bf(f1.z); o[7] = f2bf(f1.w);
        *(u16x8*)&As[r * 32 + c] = o;
      }
    }
    __syncthreads();   // staging visible (compiler drains vmcnt at barrier)

    // ---- fragments + MFMA ----
    s16x8 a[4], b[4];
#pragma unroll
    for (int i = 0; i < 4; ++i)
      a[i] = *(const s16x8*)&As[(wr + i * 16 + fr) * 32 + fq * 8];
#pragma unroll
    for (int j = 0; j < 4; ++j)
      b[j] = *(const s16x8*)&Bs[(wc + j * 16 + fr) * 32 + fq * 8];
#pragma unroll
    for (int i = 0; i < 4; ++i)
#pragma unroll
      for (int j = 0; j < 4; ++j)
        acc[i][j] = __builtin_amdgcn_mfma_f32_16x16x32_bf16(a[i], b[j], acc[i][j], 0, 0, 0);
  }

  // ---- epilogue: += bias, f32 store ----
#pragma unroll
  for (int j = 0; j < 4; ++j) {
    int n = n0 + wc + j * 16 + fr;
    float bv = bias[n];
#pragma unroll
    for (int i = 0; i < 4; ++i) {
      int mbase = m0 + wr + i * 16 + fq * 4;
#pragma unroll
      for (int e = 0; e < 4; ++e)
        out[(size_t)(mbase + e) * NOUT + n] = acc[i][j][e] + bv;
    }
  }
}

// ---------------------------------------------------------------------------
extern "C" void kernel_launch(void* const* d_in, const int* in_sizes, int n_in,
                              void* d_out, int out_size, void* d_ws, size_t ws_size,
                              hipStream_t stream)
{
  const float* x    = (const float*)d_in[0];
  const float* Wqkv = (const float*)d_in[1];
  const float* bqkv = (const float*)d_in[2];
  const float* Aq   = (const float*)d_in[3];
  const float* Bq   = (const float*)d_in[4];
  const float* Ak   = (const float*)d_in[5];
  const float* Bk   = (const float*)d_in[6];
  const float* Av   = (const float*)d_in[7];
  const float* Bv   = (const float*)d_in[8];
  float* out = (float*)d_out;

  u16* Wb = (u16*)d_ws;
  u16* xb = Wb + WB_ELEMS;

  const bool pre = ws_size >= (WB_ELEMS + XB_ELEMS) * sizeof(u16);

  prep_w<<<(NOUT * KD) / 256, 256, 0, stream>>>(Wqkv, Aq, Bq, Ak, Bk, Av, Bv, Wb);

  if (pre) {
    conv_x<<<(int)(XB_ELEMS / 8 / 256), 256, 0, stream>>>(x, xb);
    gemm_kern<true><<<(MTOK / 128) * (NOUT / 128), 256, 0, stream>>>(x, xb, Wb, bqkv, out);
  } else {
    gemm_kern<false><<<(MTOK / 128) * (NOUT / 128), 256, 0, stream>>>(x, xb, Wb, bqkv, out);
  }
}

// Round 2
// 514.910 us; speedup vs baseline: 1.0500x; 1.0500x over previous
//
#include <hip/hip_runtime.h>
#include <hip/hip_bf16.h>
#include <stdint.h>

#define DIM   768
#define NOUT  2304        // 3*DIM
#define MTOK  32768       // 8*64*64
#define KD    768
#define RANK  16

typedef float          f32x4 __attribute__((ext_vector_type(4)));
typedef short          s16x8 __attribute__((ext_vector_type(8)));
typedef unsigned short u16;
typedef u16            u16x8 __attribute__((ext_vector_type(8)));

static constexpr size_t WB_ELEMS = (size_t)NOUT * KD;   // 1,769,472
static constexpr size_t XB_ELEMS = (size_t)MTOK * KD;   // 25,165,824

// f32 -> bf16 round-to-nearest-even
__device__ __forceinline__ u16 f2bf(float f) {
  union { float f; uint32_t u; } v; v.f = f;
  uint32_t u = v.u;
  return (u16)((u + 0x7FFFu + ((u >> 16) & 1u)) >> 16);
}

__device__ __forceinline__ void gload_lds16(const void* g, const u16* l) {
  __builtin_amdgcn_global_load_lds(
      (const __attribute__((address_space(1))) unsigned int*)g,
      (__attribute__((address_space(3))) unsigned int*)l, 16, 0, 0);
}

// ---------------------------------------------------------------------------
// prep: W_eff[n][k] = Wqkv[n][k] + sum_r B_s[n%768][r] * A_s[r][k]  -> bf16
// ---------------------------------------------------------------------------
__global__ __launch_bounds__(256) void prep_w(
    const float* __restrict__ Wqkv,
    const float* __restrict__ Aq, const float* __restrict__ Bq,
    const float* __restrict__ Ak, const float* __restrict__ Bk,
    const float* __restrict__ Av, const float* __restrict__ Bv,
    u16* __restrict__ Wb)
{
  int flat = blockIdx.x * 256 + threadIdx.x;       // < NOUT*KD
  int n = flat / KD;
  int k = flat - n * KD;
  int s = n / DIM;
  int d = n - s * DIM;
  const float* A = (s == 0) ? Aq : ((s == 1) ? Ak : Av);
  const float* B = (s == 0) ? Bq : ((s == 1) ? Bk : Bv);
  float acc = Wqkv[(size_t)n * KD + k];
#pragma unroll
  for (int r = 0; r < RANK; ++r)
    acc += B[d * RANK + r] * A[r * KD + k];
  Wb[(size_t)n * KD + k] = f2bf(acc);
}

// ---------------------------------------------------------------------------
// x f32 -> bf16 (8 elems/thread)
// ---------------------------------------------------------------------------
__global__ __launch_bounds__(256) void conv_x(
    const float* __restrict__ x, u16* __restrict__ xb)
{
  size_t base = ((size_t)blockIdx.x * 256 + threadIdx.x) * 8;
  const float4* p = (const float4*)(x + base);
  float4 f0 = p[0];
  float4 f1 = p[1];
  u16x8 o;
  o[0] = f2bf(f0.x); o[1] = f2bf(f0.y); o[2] = f2bf(f0.z); o[3] = f2bf(f0.w);
  o[4] = f2bf(f1.x); o[5] = f2bf(f1.y); o[6] = f2bf(f1.z); o[7] = f2bf(f1.w);
  *(u16x8*)(xb + base) = o;
}

// ---------------------------------------------------------------------------
// GEMM 256x256 tile, BK=32, 8 waves (2M x 4N), ring-4 LDS double... quad-buffer
// depth-3 prefetch, counted vmcnt (never 0 in main loop), raw s_barrier,
// XOR-swizzled LDS (granule ^= (row>>1)&3) via pre-swizzled global source,
// s_setprio around MFMA clusters.
//
// LDS per slot: A[256][32] bf16 (16KB) + B[256][32] (16KB) = 32KB; 4 slots.
// Slot s staged by tile kt has invariant: phys granule g of row r holds
// logical k-granule g ^ ((r>>1)&3).
// ---------------------------------------------------------------------------
__global__ __launch_bounds__(512, 2) void gemm256(
    const u16* __restrict__ xb, const u16* __restrict__ Wb,
    const float* __restrict__ bias, float* __restrict__ out)
{
  extern __shared__ __attribute__((aligned(16))) u16 smem[];   // 4*16384 u16

  const int tid = threadIdx.x;
  const int l   = tid & 63;
  const int w   = tid >> 6;     // 0..7
  const int wm  = w >> 2;       // 0..1  (M half)
  const int wn  = w & 3;        // 0..3  (N quarter)
  const int fr  = l & 15;
  const int fq  = l >> 4;

  // XCD-chunked bijective swizzle: nwg = 1152 = 8 * 144
  int bid = blockIdx.x;
  int swz = (bid & 7) * 144 + (bid >> 3);
  int tm  = swz / 9;
  int tn  = swz - tm * 9;
  const int m0 = tm * 256;
  const int n0 = tn * 256;

  // ---- staging source (pre-swizzled so linear LDS dest = swizzled layout) --
  const int srow = w * 16 + (l >> 2);                 // 0..127
  const int sk   = ((l & 3) ^ ((l >> 3) & 3)) * 8;    // logical k elem offset
  const u16* gA0 = xb + (size_t)(m0 + srow) * KD + sk;
  const u16* gA1 = gA0 + (size_t)128 * KD;
  const u16* gB0 = Wb + (size_t)(n0 + srow) * KD + sk;
  const u16* gB1 = gB0 + (size_t)128 * KD;

  // ---- fragment read offsets (u16 units within slot), swizzled ------------
  const int sg = (fr >> 1) & 3;
  int aoff[8], boff[4];
#pragma unroll
  for (int i = 0; i < 8; ++i) {
    int row = wm * 128 + i * 16 + fr;
    aoff[i] = row * 32 + ((fq ^ sg) * 8);
  }
#pragma unroll
  for (int j = 0; j < 4; ++j) {
    int row = wn * 64 + j * 16 + fr;
    boff[j] = 8192 + row * 32 + ((fq ^ sg) * 8);
  }

  f32x4 acc[8][4];
#pragma unroll
  for (int i = 0; i < 8; ++i)
#pragma unroll
    for (int j = 0; j < 4; ++j) acc[i][j] = (f32x4)0.0f;

#define STAGE_A(KT) { const size_t ko = (size_t)(KT) * 32;                    \
    u16* lb = smem + (((KT) & 3) * 16384) + w * 512;                          \
    gload_lds16(gA0 + ko, lb);                                                \
    gload_lds16(gA1 + ko, lb + 4096); }

#define STAGE_B(KT) { const size_t ko = (size_t)(KT) * 32;                    \
    u16* lb = smem + (((KT) & 3) * 16384) + w * 512;                          \
    gload_lds16(gB0 + ko, lb + 8192);                                         \
    gload_lds16(gB1 + ko, lb + 12288); }

#define MFMA_ROW(AV, I)                                                       \
  acc[I][0] = __builtin_amdgcn_mfma_f32_16x16x32_bf16(AV, b0, acc[I][0], 0,0,0); \
  acc[I][1] = __builtin_amdgcn_mfma_f32_16x16x32_bf16(AV, b1, acc[I][1], 0,0,0); \
  acc[I][2] = __builtin_amdgcn_mfma_f32_16x16x32_bf16(AV, b2, acc[I][2], 0,0,0); \
  acc[I][3] = __builtin_amdgcn_mfma_f32_16x16x32_bf16(AV, b3, acc[I][3], 0,0,0);

  // Per-iteration: wait own tile-kt loads (counted), barrier, two phases of
  // {ds_read frags | issue prefetch kt+3 | setprio MFMA}.  Stage target slot
  // (kt+3)&3 == (kt-1)&3: its readers all retired before this barrier.
#define ITER(KT, VM, DOSTAGE)                                                 \
  {                                                                           \
    asm volatile("s_waitcnt vmcnt(" VM ")" ::: "memory");                     \
    __builtin_amdgcn_s_barrier();                                             \
    asm volatile("" ::: "memory");                                            \
    const u16* S = smem + ((KT) & 3) * 16384;                                 \
    s16x8 b0 = *(const s16x8*)(S + boff[0]);                                  \
    s16x8 b1 = *(const s16x8*)(S + boff[1]);                                  \
    s16x8 b2 = *(const s16x8*)(S + boff[2]);                                  \
    s16x8 b3 = *(const s16x8*)(S + boff[3]);                                  \
    s16x8 a0 = *(const s16x8*)(S + aoff[0]);                                  \
    s16x8 a1 = *(const s16x8*)(S + aoff[1]);                                  \
    s16x8 a2 = *(const s16x8*)(S + aoff[2]);                                  \
    s16x8 a3 = *(const s16x8*)(S + aoff[3]);                                  \
    if (DOSTAGE) STAGE_A((KT) + 3)                                            \
    __builtin_amdgcn_s_setprio(1);                                            \
    MFMA_ROW(a0, 0) MFMA_ROW(a1, 1) MFMA_ROW(a2, 2) MFMA_ROW(a3, 3)           \
    __builtin_amdgcn_s_setprio(0);                                            \
    __builtin_amdgcn_s_barrier();                                             \
    asm volatile("" ::: "memory");                                            \
    a0 = *(const s16x8*)(S + aoff[4]);                                        \
    a1 = *(const s16x8*)(S + aoff[5]);                                        \
    a2 = *(const s16x8*)(S + aoff[6]);                                        \
    a3 = *(const s16x8*)(S + aoff[7]);                                        \
    if (DOSTAGE) STAGE_B((KT) + 3)                                            \
    __builtin_amdgcn_s_setprio(1);                                            \
    MFMA_ROW(a0, 4) MFMA_ROW(a1, 5) MFMA_ROW(a2, 6) MFMA_ROW(a3, 7)           \
    __builtin_amdgcn_s_setprio(0);                                            \
  }

  // prologue: stage tiles 0,1,2 (12 loads/thread outstanding)
  STAGE_A(0) STAGE_B(0)
  STAGE_A(1) STAGE_B(1)
  STAGE_A(2) STAGE_B(2)

  // main loop: 24 K-tiles; stage T3..T23; drain 8 -> 8 -> 4 -> 0
#pragma unroll 4
  for (int kt = 0; kt < 20; ++kt) ITER(kt, "8", true);
  ITER(20, "8", true);
  ITER(21, "8", false);
  ITER(22, "4", false);
  ITER(23, "0", false);

#undef ITER
#undef MFMA_ROW
#undef STAGE_A
#undef STAGE_B

  // ---- epilogue: += bias, f32 store ----
#pragma unroll
  for (int j = 0; j < 4; ++j) {
    const int n  = n0 + wn * 64 + j * 16 + fr;
    const float bv = bias[n];
#pragma unroll
    for (int i = 0; i < 8; ++i) {
      const int mb = m0 + wm * 128 + i * 16 + fq * 4;
#pragma unroll
      for (int e = 0; e < 4; ++e)
        out[(size_t)(mb + e) * NOUT + n] = acc[i][j][e] + bv;
    }
  }
}

// ---------------------------------------------------------------------------
extern "C" void kernel_launch(void* const* d_in, const int* in_sizes, int n_in,
                              void* d_out, int out_size, void* d_ws, size_t ws_size,
                              hipStream_t stream)
{
  const float* x    = (const float*)d_in[0];
  const float* Wqkv = (const float*)d_in[1];
  const float* bqkv = (const float*)d_in[2];
  const float* Aq   = (const float*)d_in[3];
  const float* Bq   = (const float*)d_in[4];
  const float* Ak   = (const float*)d_in[5];
  const float* Bk   = (const float*)d_in[6];
  const float* Av   = (const float*)d_in[7];
  const float* Bv   = (const float*)d_in[8];
  float* out = (float*)d_out;

  u16* Wb = (u16*)d_ws;
  u16* xb = Wb + WB_ELEMS;

  prep_w<<<(NOUT * KD) / 256, 256, 0, stream>>>(Wqkv, Aq, Bq, Ak, Bk, Av, Bv, Wb);
  conv_x<<<(int)(XB_ELEMS / 8 / 256), 256, 0, stream>>>(x, xb);

  hipFuncSetAttribute((const void*)gemm256,
                      hipFuncAttributeMaxDynamicSharedMemorySize, 131072);
  gemm256<<<(MTOK / 256) * (NOUT / 256), 512, 131072, stream>>>(xb, Wb, bqkv, out);
}